// Round 1
// baseline (2993.739 us; speedup 1.0000x reference)
//
#include <hip/hip_runtime.h>
#include <hip/hip_bf16.h>
#include <math.h>

// MoE top-2/8: D=1024 H=4096, T=16384 tokens. Grouped-GEMM two-pass design.
// bf16 MFMA (threshold 5.3e-2 = 8*bf16eps*max|ref| budgets for this).
#define T_TOK 16384
#define D_DIM 1024
#define H_DIM 4096
#define E_EXP 8
#define TOT_ROWS (T_TOK * 2)   // every token goes to exactly 2 experts

typedef __attribute__((ext_vector_type(8))) short bf16x8;
typedef __attribute__((ext_vector_type(4))) float floatx4;

__device__ __forceinline__ unsigned short f2bf(float f) {
  union { float f; unsigned u; } v; v.f = f;
  unsigned r = v.u + 0x7fffu + ((v.u >> 16) & 1u);   // RNE
  return (unsigned short)(r >> 16);
}

// async global->LDS, 16B/lane; LDS dest is wave-uniform base + lane*16
__device__ __forceinline__ void gload_lds16(const void* g, void* l) {
  __builtin_amdgcn_global_load_lds(
      (const __attribute__((address_space(1))) void*)g,
      (__attribute__((address_space(3))) void*)l, 16, 0, 0);
}

// ---------------- gate: fp64-accurate logits, top-2, softmax ----------------
__global__ void __launch_bounds__(256) gate_kernel(
    const float* __restrict__ x, const float* __restrict__ gw,
    const float* __restrict__ gb, int* __restrict__ eids,
    float* __restrict__ wgt, int* __restrict__ counts)
{
  const int lane = threadIdx.x & 63;
  const int t = blockIdx.x * 4 + (threadIdx.x >> 6);   // one wave per token
  const float* xr = x + (size_t)t * D_DIM;
  double acc[E_EXP];
#pragma unroll
  for (int e = 0; e < E_EXP; ++e) acc[e] = 0.0;
  for (int j = 0; j < D_DIM / 64; ++j) {
    const int d = j * 64 + lane;                       // coalesced x read
    const double xv = (double)xr[d];
    const float* g = gw + d * E_EXP;
#pragma unroll
    for (int e = 0; e < E_EXP; ++e) acc[e] += xv * (double)g[e];
  }
#pragma unroll
  for (int e = 0; e < E_EXP; ++e) {
    double v = acc[e];
#pragma unroll
    for (int s = 32; s > 0; s >>= 1) v += __shfl_xor(v, s, 64);
    acc[e] = v;
  }
  if (lane == 0) {
    double l[E_EXP];
#pragma unroll
    for (int e = 0; e < E_EXP; ++e) l[e] = acc[e] + (double)gb[e];
    int e0 = 0;                                        // strict > : first index wins ties (top_k semantics)
    for (int e = 1; e < E_EXP; ++e) if (l[e] > l[e0]) e0 = e;
    int e1 = (e0 == 0) ? 1 : 0;
    for (int e = 0; e < E_EXP; ++e) if (e != e0 && l[e] > l[e1]) e1 = e;
    const double ex = exp(l[e1] - l[e0]);              // softmax over the 2 selected
    eids[t * 2] = e0; eids[t * 2 + 1] = e1;
    wgt[t * 2] = (float)(1.0 / (1.0 + ex));
    wgt[t * 2 + 1] = (float)(ex / (1.0 + ex));
    atomicAdd(&counts[e0], 1);
    atomicAdd(&counts[e1], 1);
  }
}

__global__ void prefix_kernel(const int* __restrict__ counts, int* __restrict__ offs) {
  if (threadIdx.x == 0) {
    int s = 0;
    for (int e = 0; e < E_EXP; ++e) { offs[e] = s; s += counts[e]; }
    offs[E_EXP] = s;   // == TOT_ROWS
  }
}

// ------------- scatter: assign rows, gather x row -> bf16 Xg (x2) -----------
__global__ void __launch_bounds__(256) scatter_kernel(
    const float* __restrict__ x, const int* __restrict__ eids,
    const float* __restrict__ wgt, const int* __restrict__ offs,
    int* __restrict__ cursors, int* __restrict__ rowmap,
    float* __restrict__ roww, unsigned short* __restrict__ Xg)
{
  __shared__ int rs[2];
  const int t = blockIdx.x;
  const int tid = threadIdx.x;
  if (tid < 2) {
    const int e = eids[t * 2 + tid];
    const int pos = atomicAdd(&cursors[e], 1);
    const int row = offs[e] + pos;
    rowmap[row] = t;
    roww[row] = wgt[t * 2 + tid];
    rs[tid] = row;
  }
  __syncthreads();
  const int r0 = rs[0], r1 = rs[1];
  const float4 v = ((const float4*)(x + (size_t)t * D_DIM))[tid];  // 256 thr * 4 = 1024
  ushort4 o;
  o.x = f2bf(v.x); o.y = f2bf(v.y); o.z = f2bf(v.z); o.w = f2bf(v.w);
  ((ushort4*)(Xg + (size_t)r0 * D_DIM))[tid] = o;
  ((ushort4*)(Xg + (size_t)r1 * D_DIM))[tid] = o;
}

// --------- weight transpose+convert: src fp32 [E][R][C] -> dst bf16 [E][C][R]
__global__ void __launch_bounds__(256) transpose_conv(
    const float* __restrict__ src, unsigned short* __restrict__ dst, int R, int C)
{
  __shared__ float tile[32][33];
  const int tx = threadIdx.x, ty = threadIdx.y;   // 32 x 8
  const size_t ebase = (size_t)blockIdx.z * R * C;
  const int c0 = blockIdx.x * 32, r0 = blockIdx.y * 32;
  const float* s = src + ebase;
#pragma unroll
  for (int j = 0; j < 4; ++j)
    tile[ty + j * 8][tx] = s[(size_t)(r0 + ty + j * 8) * C + c0 + tx];
  __syncthreads();
  unsigned short* d = dst + ebase;
#pragma unroll
  for (int j = 0; j < 4; ++j)
    d[(size_t)(c0 + ty + j * 8) * R + r0 + tx] = f2bf(tile[tx][ty + j * 8]);
}

__global__ void zero_kernel(float4* __restrict__ p, int n4) {
  const int i = blockIdx.x * blockDim.x + threadIdx.x;
  if (i < n4) p[i] = make_float4(0.f, 0.f, 0.f, 0.f);
}

__global__ void init_small_kernel(int* __restrict__ p) {
  if (threadIdx.x < 16) p[threadIdx.x] = 0;   // counts[8] + cursors[8]
}

// ------------------- GEMM1: Hbuf = relu(Xg @ W1t^T + b1) --------------------
// m97 structure: 128x128 tile, BK=32, 16x16x32 bf16 MFMA, width-16 global_load_lds
__global__ void __launch_bounds__(256) gemm1_kernel(
    const unsigned short* __restrict__ Xg,    // [TOT][1024]
    const unsigned short* __restrict__ W1t,   // [E][4096][1024] (n-major, k-contig)
    const float* __restrict__ b1,             // [E][4096]
    unsigned short* __restrict__ Hbuf,        // [TOT][4096]
    const int* __restrict__ offs)
{
  __shared__ unsigned short As[128 * 32];
  __shared__ unsigned short Bs[128 * 32];
  const int e  = blockIdx.x >> 7;
  const int mt = blockIdx.x & 127;
  const int nt = blockIdx.y;                  // 0..31
  const int row0 = offs[e];
  const int rows = offs[e + 1] - row0;
  if (mt * 128 >= rows) return;               // early exit on oversized grid

  const int tid = threadIdx.x, wave = tid >> 6, lane = tid & 63;
  const int wm = wave & 1, wn = wave >> 1;
  floatx4 acc[4][4];
  const floatx4 zf = {0.f, 0.f, 0.f, 0.f};
#pragma unroll
  for (int mi = 0; mi < 4; ++mi)
#pragma unroll
    for (int ni = 0; ni < 4; ++ni) acc[mi][ni] = zf;

  const unsigned short* Wb = W1t + ((size_t)e * H_DIM + nt * 128) * D_DIM;
  const int arow = wave * 32 + (lane >> 2);   // row within 128-tile (16 rows/instr)
  const int kcol = (lane & 3) * 8;            // k element offset within BK

  for (int k0 = 0; k0 < D_DIM; k0 += 32) {
    __syncthreads();
#pragma unroll
    for (int i = 0; i < 2; ++i) {
      int gr = row0 + mt * 128 + arow + i * 16;
      gr = gr < TOT_ROWS - 1 ? gr : TOT_ROWS - 1;   // clamp: never read past Xg
      gload_lds16(Xg + (size_t)gr * D_DIM + k0 + kcol, &As[(wave * 32 + i * 16) * 32]);
      gload_lds16(Wb + (size_t)(arow + i * 16) * D_DIM + k0 + kcol,
                  &Bs[(wave * 32 + i * 16) * 32]);
    }
    __syncthreads();
    bf16x8 af[4], bb[4];
#pragma unroll
    for (int mi = 0; mi < 4; ++mi)
      af[mi] = *(const bf16x8*)&As[(wm * 64 + mi * 16 + (lane & 15)) * 32 + (lane >> 4) * 8];
#pragma unroll
    for (int ni = 0; ni < 4; ++ni)
      bb[ni] = *(const bf16x8*)&Bs[(wn * 64 + ni * 16 + (lane & 15)) * 32 + (lane >> 4) * 8];
#pragma unroll
    for (int mi = 0; mi < 4; ++mi)
#pragma unroll
      for (int ni = 0; ni < 4; ++ni)
        acc[mi][ni] = __builtin_amdgcn_mfma_f32_16x16x32_bf16(af[mi], bb[ni], acc[mi][ni], 0, 0, 0);
  }

  const float* bias = b1 + e * H_DIM;
#pragma unroll
  for (int mi = 0; mi < 4; ++mi) {
    const int rbase = mt * 128 + wm * 64 + mi * 16 + (lane >> 4) * 4;
#pragma unroll
    for (int ni = 0; ni < 4; ++ni) {
      const int n = nt * 128 + wn * 64 + ni * 16 + (lane & 15);
      const floatx4 c = acc[mi][ni];
#pragma unroll
      for (int i = 0; i < 4; ++i) {
        const int r = rbase + i;
        if (r < rows) {
          float v = c[i] + bias[n];
          v = v > 0.f ? v : 0.f;                      // relu
          Hbuf[(size_t)(row0 + r) * H_DIM + n] = f2bf(v);
        }
      }
    }
  }
}

// --------- GEMM2: out[token] += w * (Hbuf @ W2t^T + b2)  (atomic f32) -------
__global__ void __launch_bounds__(256) gemm2_kernel(
    const unsigned short* __restrict__ Hbuf,  // [TOT][4096]
    const unsigned short* __restrict__ W2t,   // [E][1024][4096]
    const float* __restrict__ b2,             // [E][1024]
    const int* __restrict__ offs,
    const int* __restrict__ rowmap, const float* __restrict__ roww,
    float* __restrict__ out)
{
  __shared__ unsigned short As[128 * 32];
  __shared__ unsigned short Bs[128 * 32];
  const int e  = blockIdx.x >> 7;
  const int mt = blockIdx.x & 127;
  const int nt = blockIdx.y;                  // 0..7
  const int row0 = offs[e];
  const int rows = offs[e + 1] - row0;
  if (mt * 128 >= rows) return;

  const int tid = threadIdx.x, wave = tid >> 6, lane = tid & 63;
  const int wm = wave & 1, wn = wave >> 1;
  floatx4 acc[4][4];
  const floatx4 zf = {0.f, 0.f, 0.f, 0.f};
#pragma unroll
  for (int mi = 0; mi < 4; ++mi)
#pragma unroll
    for (int ni = 0; ni < 4; ++ni) acc[mi][ni] = zf;

  const unsigned short* Wb = W2t + ((size_t)e * D_DIM + nt * 128) * H_DIM;
  const int arow = wave * 32 + (lane >> 2);
  const int kcol = (lane & 3) * 8;

  for (int k0 = 0; k0 < H_DIM; k0 += 32) {
    __syncthreads();
#pragma unroll
    for (int i = 0; i < 2; ++i) {
      int gr = row0 + mt * 128 + arow + i * 16;
      gr = gr < TOT_ROWS - 1 ? gr : TOT_ROWS - 1;
      gload_lds16(Hbuf + (size_t)gr * H_DIM + k0 + kcol, &As[(wave * 32 + i * 16) * 32]);
      gload_lds16(Wb + (size_t)(arow + i * 16) * H_DIM + k0 + kcol,
                  &Bs[(wave * 32 + i * 16) * 32]);
    }
    __syncthreads();
    bf16x8 af[4], bb[4];
#pragma unroll
    for (int mi = 0; mi < 4; ++mi)
      af[mi] = *(const bf16x8*)&As[(wm * 64 + mi * 16 + (lane & 15)) * 32 + (lane >> 4) * 8];
#pragma unroll
    for (int ni = 0; ni < 4; ++ni)
      bb[ni] = *(const bf16x8*)&Bs[(wn * 64 + ni * 16 + (lane & 15)) * 32 + (lane >> 4) * 8];
#pragma unroll
    for (int mi = 0; mi < 4; ++mi)
#pragma unroll
      for (int ni = 0; ni < 4; ++ni)
        acc[mi][ni] = __builtin_amdgcn_mfma_f32_16x16x32_bf16(af[mi], bb[ni], acc[mi][ni], 0, 0, 0);
  }

  const float* bias = b2 + e * D_DIM;
#pragma unroll
  for (int mi = 0; mi < 4; ++mi) {
    const int rbase = mt * 128 + wm * 64 + mi * 16 + (lane >> 4) * 4;
#pragma unroll
    for (int i = 0; i < 4; ++i) {
      const int r = rbase + i;
      if (r < rows) {
        const int grow = row0 + r;
        const int tok = rowmap[grow];
        const float w = roww[grow];
        float* orow = out + (size_t)tok * D_DIM;
#pragma unroll
        for (int ni = 0; ni < 4; ++ni) {
          const int n = nt * 128 + wn * 64 + ni * 16 + (lane & 15);
          atomicAdd(orow + n, w * (acc[mi][ni][i] + bias[n]));
        }
      }
    }
  }
}

extern "C" void kernel_launch(void* const* d_in, const int* in_sizes, int n_in,
                              void* d_out, int out_size, void* d_ws, size_t ws_size,
                              hipStream_t stream) {
  const float* x      = (const float*)d_in[0];
  const float* gate_w = (const float*)d_in[1];
  const float* gate_b = (const float*)d_in[2];
  const float* W1     = (const float*)d_in[3];
  const float* b1     = (const float*)d_in[4];
  const float* W2     = (const float*)d_in[5];
  const float* b2     = (const float*)d_in[6];
  float* out = (float*)d_out;

  char* ws = (char*)d_ws;
  const size_t MB = 1024 * 1024;
  int*   counts  = (int*)(ws + 0);          // [8]
  int*   cursors = (int*)(ws + 32);         // [8]
  int*   offs    = (int*)(ws + 64);         // [9]
  int*   eids    = (int*)(ws + 256);                    // [T*2]
  float* wgt     = (float*)(ws + 256 + 131072);         // [T*2]
  int*   rowmap  = (int*)(ws + 256 + 262144);           // [TOT]
  float* roww    = (float*)(ws + 256 + 393216);         // [TOT]
  unsigned short* Xg   = (unsigned short*)(ws + MB);                    // 64 MB
  unsigned short* Hbuf = (unsigned short*)(ws + MB + 64 * MB);          // 256 MB
  unsigned short* W1t  = (unsigned short*)(ws + MB + (64 + 256) * MB);  // 64 MB
  unsigned short* W2t  = (unsigned short*)(ws + MB + (64 + 256 + 64) * MB); // 64 MB
  const size_t need = MB + (64 + 256 + 64 + 64) * MB;

  // out must be zeroed every call (harness poisons with 0xAA)
  zero_kernel<<<(out_size / 4 + 255) / 256, 256, 0, stream>>>((float4*)out, out_size / 4);
  if (ws_size < need) return;  // signals ws shortage (out stays zero) without OOB writes

  init_small_kernel<<<1, 64, 0, stream>>>(counts);
  gate_kernel<<<T_TOK / 4, 256, 0, stream>>>(x, gate_w, gate_b, eids, wgt, counts);
  prefix_kernel<<<1, 64, 0, stream>>>(counts, offs);
  scatter_kernel<<<T_TOK, 256, 0, stream>>>(x, eids, wgt, offs, cursors, rowmap, roww, Xg);
  transpose_conv<<<dim3(H_DIM / 32, D_DIM / 32, E_EXP), dim3(32, 8), 0, stream>>>(W1, W1t, D_DIM, H_DIM);
  transpose_conv<<<dim3(D_DIM / 32, H_DIM / 32, E_EXP), dim3(32, 8), 0, stream>>>(W2, W2t, H_DIM, D_DIM);
  gemm1_kernel<<<dim3(E_EXP * 128, H_DIM / 128), 256, 0, stream>>>(Xg, W1t, b1, Hbuf, offs);
  gemm2_kernel<<<dim3(E_EXP * 128, D_DIM / 128), 256, 0, stream>>>(Hbuf, W2t, b2, offs, rowmap, roww, out);
}

// Round 2
// 1792.761 us; speedup vs baseline: 1.6699x; 1.6699x over previous
//
#include <hip/hip_runtime.h>
#include <hip/hip_bf16.h>
#include <math.h>

// MoE top-2/8: D=1024 H=4096, T=16384 tokens. Grouped-GEMM two-pass design.
// R2: atomic-free routing (counting sort), gathered-A GEMM1 (no Xg scatter).
#define T_TOK 16384
#define D_DIM 1024
#define H_DIM 4096
#define E_EXP 8
#define TOT_ROWS (T_TOK * 2)   // every token goes to exactly 2 experts
#define NBLK 64                // routing blocks; SLOTS/NBLK = 512 slots/block

typedef __attribute__((ext_vector_type(8))) short bf16x8;
typedef __attribute__((ext_vector_type(4))) float floatx4;

__device__ __forceinline__ unsigned short f2bf(float f) {
  union { float f; unsigned u; } v; v.f = f;
  unsigned r = v.u + 0x7fffu + ((v.u >> 16) & 1u);   // RNE
  return (unsigned short)(r >> 16);
}

// async global->LDS, 16B/lane; LDS dest is wave-uniform base + lane*16
__device__ __forceinline__ void gload_lds16(const void* g, void* l) {
  __builtin_amdgcn_global_load_lds(
      (const __attribute__((address_space(1))) void*)g,
      (__attribute__((address_space(3))) void*)l, 16, 0, 0);
}

// ---------------- gate: fp64-accurate logits, top-2, softmax ----------------
// NO global atomics (R1 post-mortem: 2 atomics/token on one cacheline = ~800us).
__global__ void __launch_bounds__(256) gate_kernel(
    const float* __restrict__ x, const float* __restrict__ gw,
    const float* __restrict__ gb, int* __restrict__ eids,
    float* __restrict__ wgt)
{
  const int lane = threadIdx.x & 63;
  const int t = blockIdx.x * 4 + (threadIdx.x >> 6);   // one wave per token
  const float* xr = x + (size_t)t * D_DIM;
  double acc[E_EXP];
#pragma unroll
  for (int e = 0; e < E_EXP; ++e) acc[e] = 0.0;
  for (int j = 0; j < D_DIM / 64; ++j) {
    const int d = j * 64 + lane;                       // coalesced x read
    const double xv = (double)xr[d];
    const float* g = gw + d * E_EXP;
#pragma unroll
    for (int e = 0; e < E_EXP; ++e) acc[e] += xv * (double)g[e];
  }
#pragma unroll
  for (int e = 0; e < E_EXP; ++e) {
    double v = acc[e];
#pragma unroll
    for (int s = 32; s > 0; s >>= 1) v += __shfl_xor(v, s, 64);
    acc[e] = v;
  }
  if (lane == 0) {
    double l[E_EXP];
#pragma unroll
    for (int e = 0; e < E_EXP; ++e) l[e] = acc[e] + (double)gb[e];
    int e0 = 0;                                        // strict > : first index wins ties (top_k semantics)
    for (int e = 1; e < E_EXP; ++e) if (l[e] > l[e0]) e0 = e;
    int e1 = (e0 == 0) ? 1 : 0;
    for (int e = 0; e < E_EXP; ++e) if (e != e0 && l[e] > l[e1]) e1 = e;
    const double ex = exp(l[e1] - l[e0]);              // softmax over the 2 selected
    eids[t * 2] = e0; eids[t * 2 + 1] = e1;
    wgt[t * 2] = (float)(1.0 / (1.0 + ex));
    wgt[t * 2 + 1] = (float)(ex / (1.0 + ex));
  }
}

// ------------- routing pass 1: per-block expert histogram (LDS only) --------
__global__ void __launch_bounds__(256) hist_kernel(
    const int* __restrict__ eids, int* __restrict__ blockHist)
{
  __shared__ int h[E_EXP];
  const int tid = threadIdx.x, blk = blockIdx.x;
  if (tid < E_EXP) h[tid] = 0;
  __syncthreads();
  const int s0 = blk * (TOT_ROWS / NBLK);
  for (int i = tid; i < TOT_ROWS / NBLK; i += 256)
    atomicAdd(&h[eids[s0 + i]], 1);                    // LDS atomic: cheap
  __syncthreads();
  if (tid < E_EXP) blockHist[blk * E_EXP + tid] = h[tid];
}

// ------------- routing pass 2: serial prefix over 64x8 ints -----------------
__global__ void prefix_kernel(const int* __restrict__ blockHist,
                              int* __restrict__ blockBase, int* __restrict__ offs)
{
  if (threadIdx.x == 0) {
    int tot[E_EXP];
    for (int e = 0; e < E_EXP; ++e) {
      int s = 0;
      for (int b = 0; b < NBLK; ++b) s += blockHist[b * E_EXP + e];
      tot[e] = s;
    }
    int run = 0;
    for (int e = 0; e < E_EXP; ++e) { offs[e] = run; run += tot[e]; }
    offs[E_EXP] = run;                                 // == TOT_ROWS
    for (int e = 0; e < E_EXP; ++e) {
      int r = offs[e];
      for (int b = 0; b < NBLK; ++b) { blockBase[b * E_EXP + e] = r; r += blockHist[b * E_EXP + e]; }
    }
  }
}

// ------------- routing pass 3: assign rows (LDS-atomic local ranks) ---------
__global__ void __launch_bounds__(256) assign_kernel(
    const int* __restrict__ eids, const float* __restrict__ wgt,
    const int* __restrict__ blockBase,
    int* __restrict__ rowmap, float* __restrict__ roww)
{
  __shared__ int base[E_EXP];
  __shared__ int cnt[E_EXP];
  const int tid = threadIdx.x, blk = blockIdx.x;
  if (tid < E_EXP) { base[tid] = blockBase[blk * E_EXP + tid]; cnt[tid] = 0; }
  __syncthreads();
  const int s0 = blk * (TOT_ROWS / NBLK);
  for (int i = tid; i < TOT_ROWS / NBLK; i += 256) {
    const int s = s0 + i;
    const int e = eids[s];
    const int r = base[e] + atomicAdd(&cnt[e], 1);     // unique row in expert region
    rowmap[r] = s >> 1;                                // token index
    roww[r] = wgt[s];
  }
}

// ------------- x -> bf16 straight convert (no scatter) ----------------------
__global__ void __launch_bounds__(256) convert_x(
    const float* __restrict__ x, unsigned short* __restrict__ xb)
{
  const size_t i = (size_t)blockIdx.x * 256 + threadIdx.x;   // float4 granularity
  const float4 v = ((const float4*)x)[i];
  ushort4 o;
  o.x = f2bf(v.x); o.y = f2bf(v.y); o.z = f2bf(v.z); o.w = f2bf(v.w);
  ((ushort4*)xb)[i] = o;
}

// --------- weight transpose+convert: src fp32 [E][R][C] -> dst bf16 [E][C][R]
__global__ void __launch_bounds__(256) transpose_conv(
    const float* __restrict__ src, unsigned short* __restrict__ dst, int R, int C)
{
  __shared__ float tile[32][33];
  const int tx = threadIdx.x, ty = threadIdx.y;   // 32 x 8
  const size_t ebase = (size_t)blockIdx.z * R * C;
  const int c0 = blockIdx.x * 32, r0 = blockIdx.y * 32;
  const float* s = src + ebase;
#pragma unroll
  for (int j = 0; j < 4; ++j)
    tile[ty + j * 8][tx] = s[(size_t)(r0 + ty + j * 8) * C + c0 + tx];
  __syncthreads();
  unsigned short* d = dst + ebase;
#pragma unroll
  for (int j = 0; j < 4; ++j)
    d[(size_t)(c0 + ty + j * 8) * R + r0 + tx] = f2bf(tile[tx][ty + j * 8]);
}

__global__ void zero_kernel(float4* __restrict__ p, int n4) {
  const int i = blockIdx.x * blockDim.x + threadIdx.x;
  if (i < n4) p[i] = make_float4(0.f, 0.f, 0.f, 0.f);
}

// ------------------- GEMM1: Hbuf = relu(gather(xb) @ W1t^T + b1) ------------
// m97 structure: 128x128 tile, BK=32, 16x16x32 bf16 MFMA, width-16 global_load_lds.
// A rows gathered through rowmap (per-lane global address; pointers hoisted).
__global__ void __launch_bounds__(256) gemm1_kernel(
    const unsigned short* __restrict__ xb,    // [T][1024] bf16
    const unsigned short* __restrict__ W1t,   // [E][4096][1024] (n-major, k-contig)
    const float* __restrict__ b1,             // [E][4096]
    unsigned short* __restrict__ Hbuf,        // [TOT][4096]
    const int* __restrict__ offs, const int* __restrict__ rowmap)
{
  __shared__ unsigned short As[128 * 32];
  __shared__ unsigned short Bs[128 * 32];
  const int e  = blockIdx.x >> 7;
  const int mt = blockIdx.x & 127;
  const int nt = blockIdx.y;                  // 0..31
  const int row0 = offs[e];
  const int rows = offs[e + 1] - row0;
  if (mt * 128 >= rows) return;               // early exit on oversized grid

  const int tid = threadIdx.x, wave = tid >> 6, lane = tid & 63;
  const int wm = wave & 1, wn = wave >> 1;
  floatx4 acc[4][4];
  const floatx4 zf = {0.f, 0.f, 0.f, 0.f};
#pragma unroll
  for (int mi = 0; mi < 4; ++mi)
#pragma unroll
    for (int ni = 0; ni < 4; ++ni) acc[mi][ni] = zf;

  const unsigned short* Wb = W1t + ((size_t)e * H_DIM + nt * 128) * D_DIM;
  const int arow = wave * 32 + (lane >> 2);   // row within 128-tile (16 rows/instr)
  const int kcol = (lane & 3) * 8;            // k element offset within BK

  // hoist gathered A-row pointers out of the K-loop
  const unsigned short* aptr[2];
  const unsigned short* bptr[2];
#pragma unroll
  for (int i = 0; i < 2; ++i) {
    const int r = mt * 128 + arow + i * 16;
    const int tok = rowmap[row0 + (r < rows ? r : 0)];   // clamp: valid token
    aptr[i] = xb + (size_t)tok * D_DIM + kcol;
    bptr[i] = Wb + (size_t)(arow + i * 16) * D_DIM + kcol;
  }

  for (int k0 = 0; k0 < D_DIM; k0 += 32) {
    __syncthreads();
#pragma unroll
    for (int i = 0; i < 2; ++i) {
      gload_lds16(aptr[i] + k0, &As[(wave * 32 + i * 16) * 32]);
      gload_lds16(bptr[i] + k0, &Bs[(wave * 32 + i * 16) * 32]);
    }
    __syncthreads();
    bf16x8 af[4], bb[4];
#pragma unroll
    for (int mi = 0; mi < 4; ++mi)
      af[mi] = *(const bf16x8*)&As[(wm * 64 + mi * 16 + (lane & 15)) * 32 + (lane >> 4) * 8];
#pragma unroll
    for (int ni = 0; ni < 4; ++ni)
      bb[ni] = *(const bf16x8*)&Bs[(wn * 64 + ni * 16 + (lane & 15)) * 32 + (lane >> 4) * 8];
#pragma unroll
    for (int mi = 0; mi < 4; ++mi)
#pragma unroll
      for (int ni = 0; ni < 4; ++ni)
        acc[mi][ni] = __builtin_amdgcn_mfma_f32_16x16x32_bf16(af[mi], bb[ni], acc[mi][ni], 0, 0, 0);
  }

  const float* bias = b1 + e * H_DIM;
#pragma unroll
  for (int mi = 0; mi < 4; ++mi) {
    const int rbase = mt * 128 + wm * 64 + mi * 16 + (lane >> 4) * 4;
#pragma unroll
    for (int ni = 0; ni < 4; ++ni) {
      const int n = nt * 128 + wn * 64 + ni * 16 + (lane & 15);
      const floatx4 c = acc[mi][ni];
#pragma unroll
      for (int i = 0; i < 4; ++i) {
        const int r = rbase + i;
        if (r < rows) {
          float v = c[i] + bias[n];
          v = v > 0.f ? v : 0.f;                      // relu
          Hbuf[(size_t)(row0 + r) * H_DIM + n] = f2bf(v);
        }
      }
    }
  }
}

// --------- GEMM2: out[token] += w * (Hbuf @ W2t^T + b2)  (atomic f32) -------
__global__ void __launch_bounds__(256) gemm2_kernel(
    const unsigned short* __restrict__ Hbuf,  // [TOT][4096]
    const unsigned short* __restrict__ W2t,   // [E][1024][4096]
    const float* __restrict__ b2,             // [E][1024]
    const int* __restrict__ offs,
    const int* __restrict__ rowmap, const float* __restrict__ roww,
    float* __restrict__ out)
{
  __shared__ unsigned short As[128 * 32];
  __shared__ unsigned short Bs[128 * 32];
  const int e  = blockIdx.x >> 7;
  const int mt = blockIdx.x & 127;
  const int nt = blockIdx.y;                  // 0..7
  const int row0 = offs[e];
  const int rows = offs[e + 1] - row0;
  if (mt * 128 >= rows) return;

  const int tid = threadIdx.x, wave = tid >> 6, lane = tid & 63;
  const int wm = wave & 1, wn = wave >> 1;
  floatx4 acc[4][4];
  const floatx4 zf = {0.f, 0.f, 0.f, 0.f};
#pragma unroll
  for (int mi = 0; mi < 4; ++mi)
#pragma unroll
    for (int ni = 0; ni < 4; ++ni) acc[mi][ni] = zf;

  const unsigned short* Wb = W2t + ((size_t)e * D_DIM + nt * 128) * H_DIM;
  const int arow = wave * 32 + (lane >> 2);
  const int kcol = (lane & 3) * 8;

  const unsigned short* aptr[2];
  const unsigned short* bptr[2];
#pragma unroll
  for (int i = 0; i < 2; ++i) {
    int gr = row0 + mt * 128 + arow + i * 16;
    gr = gr < TOT_ROWS - 1 ? gr : TOT_ROWS - 1;        // clamp: never read past Hbuf
    aptr[i] = Hbuf + (size_t)gr * H_DIM + kcol;
    bptr[i] = Wb + (size_t)(arow + i * 16) * H_DIM + kcol;
  }

  for (int k0 = 0; k0 < H_DIM; k0 += 32) {
    __syncthreads();
#pragma unroll
    for (int i = 0; i < 2; ++i) {
      gload_lds16(aptr[i] + k0, &As[(wave * 32 + i * 16) * 32]);
      gload_lds16(bptr[i] + k0, &Bs[(wave * 32 + i * 16) * 32]);
    }
    __syncthreads();
    bf16x8 af[4], bb[4];
#pragma unroll
    for (int mi = 0; mi < 4; ++mi)
      af[mi] = *(const bf16x8*)&As[(wm * 64 + mi * 16 + (lane & 15)) * 32 + (lane >> 4) * 8];
#pragma unroll
    for (int ni = 0; ni < 4; ++ni)
      bb[ni] = *(const bf16x8*)&Bs[(wn * 64 + ni * 16 + (lane & 15)) * 32 + (lane >> 4) * 8];
#pragma unroll
    for (int mi = 0; mi < 4; ++mi)
#pragma unroll
      for (int ni = 0; ni < 4; ++ni)
        acc[mi][ni] = __builtin_amdgcn_mfma_f32_16x16x32_bf16(af[mi], bb[ni], acc[mi][ni], 0, 0, 0);
  }

  const float* bias = b2 + e * D_DIM;
#pragma unroll
  for (int mi = 0; mi < 4; ++mi) {
    const int rbase = mt * 128 + wm * 64 + mi * 16 + (lane >> 4) * 4;
#pragma unroll
    for (int i = 0; i < 4; ++i) {
      const int r = rbase + i;
      if (r < rows) {
        const int grow = row0 + r;
        const int tok = rowmap[grow];
        const float w = roww[grow];
        float* orow = out + (size_t)tok * D_DIM;
#pragma unroll
        for (int ni = 0; ni < 4; ++ni) {
          const int n = nt * 128 + wn * 64 + ni * 16 + (lane & 15);
          atomicAdd(orow + n, w * (acc[mi][ni][i] + bias[n]));
        }
      }
    }
  }
}

extern "C" void kernel_launch(void* const* d_in, const int* in_sizes, int n_in,
                              void* d_out, int out_size, void* d_ws, size_t ws_size,
                              hipStream_t stream) {
  const float* x      = (const float*)d_in[0];
  const float* gate_w = (const float*)d_in[1];
  const float* gate_b = (const float*)d_in[2];
  const float* W1     = (const float*)d_in[3];
  const float* b1     = (const float*)d_in[4];
  const float* W2     = (const float*)d_in[5];
  const float* b2     = (const float*)d_in[6];
  float* out = (float*)d_out;

  char* ws = (char*)d_ws;
  const size_t MB = 1024 * 1024;
  int*   offs      = (int*)(ws + 0);                    // [9]
  int*   blockHist = (int*)(ws + 4096);                 // [64*8]
  int*   blockBase = (int*)(ws + 8192);                 // [64*8]
  int*   eids      = (int*)(ws + 16384);                // [T*2] = 128 KB
  float* wgt       = (float*)(ws + 16384 + 131072);     // [T*2]
  int*   rowmap    = (int*)(ws + 16384 + 262144);       // [TOT]
  float* roww      = (float*)(ws + 16384 + 393216);     // [TOT]
  unsigned short* xb   = (unsigned short*)(ws + MB);                    // 32 MB
  unsigned short* Hbuf = (unsigned short*)(ws + MB + 32 * MB);          // 256 MB
  unsigned short* W1t  = (unsigned short*)(ws + MB + (32 + 256) * MB);  // 64 MB
  unsigned short* W2t  = (unsigned short*)(ws + MB + (32 + 256 + 64) * MB); // 64 MB
  const size_t need = MB + (32 + 256 + 64 + 64) * MB;

  // out must be zeroed every call (harness poisons with 0xAA)
  zero_kernel<<<(out_size / 4 + 255) / 256, 256, 0, stream>>>((float4*)out, out_size / 4);
  if (ws_size < need) return;  // signals ws shortage (out stays zero) without OOB writes

  gate_kernel<<<T_TOK / 4, 256, 0, stream>>>(x, gate_w, gate_b, eids, wgt);
  hist_kernel<<<NBLK, 256, 0, stream>>>(eids, blockHist);
  prefix_kernel<<<1, 64, 0, stream>>>(blockHist, blockBase, offs);
  assign_kernel<<<NBLK, 256, 0, stream>>>(eids, wgt, blockBase, rowmap, roww);
  convert_x<<<(T_TOK * D_DIM / 4) / 256, 256, 0, stream>>>(x, xb);
  transpose_conv<<<dim3(H_DIM / 32, D_DIM / 32, E_EXP), dim3(32, 8), 0, stream>>>(W1, W1t, D_DIM, H_DIM);
  transpose_conv<<<dim3(D_DIM / 32, H_DIM / 32, E_EXP), dim3(32, 8), 0, stream>>>(W2, W2t, H_DIM, D_DIM);
  gemm1_kernel<<<dim3(E_EXP * 128, H_DIM / 128), 256, 0, stream>>>(xb, W1t, b1, Hbuf, offs, rowmap);
  gemm2_kernel<<<dim3(E_EXP * 128, D_DIM / 128), 256, 0, stream>>>(Hbuf, W2t, b2, offs, rowmap, roww, out);
}

// Round 3
// 1386.526 us; speedup vs baseline: 2.1592x; 1.2930x over previous
//
#include <hip/hip_runtime.h>
#include <hip/hip_bf16.h>
#include <math.h>

// MoE top-2/8: D=1024 H=4096, T=16384 tokens. Grouped-GEMM two-pass design.
// R3: XCD-aware swizzle (A-tile sharers on same XCD), atomic-free epilogue
// (Ybuf + combine), Ybuf overlaid on dead W1t.
#define T_TOK 16384
#define D_DIM 1024
#define H_DIM 4096
#define E_EXP 8
#define TOT_ROWS (T_TOK * 2)   // every token goes to exactly 2 experts
#define NBLK 64                // routing blocks

typedef __attribute__((ext_vector_type(8))) short bf16x8;
typedef __attribute__((ext_vector_type(4))) float floatx4;

__device__ __forceinline__ unsigned short f2bf(float f) {
  union { float f; unsigned u; } v; v.f = f;
  unsigned r = v.u + 0x7fffu + ((v.u >> 16) & 1u);   // RNE
  return (unsigned short)(r >> 16);
}
__device__ __forceinline__ float bf2f(unsigned short s) {
  union { unsigned u; float f; } v; v.u = ((unsigned)s) << 16;
  return v.f;
}

// async global->LDS, 16B/lane; LDS dest is wave-uniform base + lane*16
__device__ __forceinline__ void gload_lds16(const void* g, void* l) {
  __builtin_amdgcn_global_load_lds(
      (const __attribute__((address_space(1))) void*)g,
      (__attribute__((address_space(3))) void*)l, 16, 0, 0);
}

// ---------------- gate: fp64-accurate logits, top-2, softmax ----------------
__global__ void __launch_bounds__(256) gate_kernel(
    const float* __restrict__ x, const float* __restrict__ gw,
    const float* __restrict__ gb, int* __restrict__ eids,
    float* __restrict__ wgt)
{
  const int lane = threadIdx.x & 63;
  const int t = blockIdx.x * 4 + (threadIdx.x >> 6);   // one wave per token
  const float* xr = x + (size_t)t * D_DIM;
  double acc[E_EXP];
#pragma unroll
  for (int e = 0; e < E_EXP; ++e) acc[e] = 0.0;
  for (int j = 0; j < D_DIM / 64; ++j) {
    const int d = j * 64 + lane;                       // coalesced x read
    const double xv = (double)xr[d];
    const float* g = gw + d * E_EXP;
#pragma unroll
    for (int e = 0; e < E_EXP; ++e) acc[e] += xv * (double)g[e];
  }
#pragma unroll
  for (int e = 0; e < E_EXP; ++e) {
    double v = acc[e];
#pragma unroll
    for (int s = 32; s > 0; s >>= 1) v += __shfl_xor(v, s, 64);
    acc[e] = v;
  }
  if (lane == 0) {
    double l[E_EXP];
#pragma unroll
    for (int e = 0; e < E_EXP; ++e) l[e] = acc[e] + (double)gb[e];
    int e0 = 0;                                        // strict > : first index wins ties
    for (int e = 1; e < E_EXP; ++e) if (l[e] > l[e0]) e0 = e;
    int e1 = (e0 == 0) ? 1 : 0;
    for (int e = 0; e < E_EXP; ++e) if (e != e0 && l[e] > l[e1]) e1 = e;
    const double ex = exp(l[e1] - l[e0]);              // softmax over the 2 selected
    eids[t * 2] = e0; eids[t * 2 + 1] = e1;
    wgt[t * 2] = (float)(1.0 / (1.0 + ex));
    wgt[t * 2 + 1] = (float)(ex / (1.0 + ex));
  }
}

// ------------- routing pass 1: per-block expert histogram (LDS only) --------
__global__ void __launch_bounds__(256) hist_kernel(
    const int* __restrict__ eids, int* __restrict__ blockHist)
{
  __shared__ int h[E_EXP];
  const int tid = threadIdx.x, blk = blockIdx.x;
  if (tid < E_EXP) h[tid] = 0;
  __syncthreads();
  const int s0 = blk * (TOT_ROWS / NBLK);
  for (int i = tid; i < TOT_ROWS / NBLK; i += 256)
    atomicAdd(&h[eids[s0 + i]], 1);                    // LDS atomic: cheap
  __syncthreads();
  if (tid < E_EXP) blockHist[blk * E_EXP + tid] = h[tid];
}

// ------------- routing pass 2: serial prefix over 64x8 ints -----------------
__global__ void prefix_kernel(const int* __restrict__ blockHist,
                              int* __restrict__ blockBase, int* __restrict__ offs)
{
  if (threadIdx.x == 0) {
    int tot[E_EXP];
    for (int e = 0; e < E_EXP; ++e) {
      int s = 0;
      for (int b = 0; b < NBLK; ++b) s += blockHist[b * E_EXP + e];
      tot[e] = s;
    }
    int run = 0;
    for (int e = 0; e < E_EXP; ++e) { offs[e] = run; run += tot[e]; }
    offs[E_EXP] = run;                                 // == TOT_ROWS
    for (int e = 0; e < E_EXP; ++e) {
      int r = offs[e];
      for (int b = 0; b < NBLK; ++b) { blockBase[b * E_EXP + e] = r; r += blockHist[b * E_EXP + e]; }
    }
  }
}

// ------------- routing pass 3: assign rows + inverse map --------------------
__global__ void __launch_bounds__(256) assign_kernel(
    const int* __restrict__ eids, const float* __restrict__ wgt,
    const int* __restrict__ blockBase,
    int* __restrict__ rowmap, int* __restrict__ invrow)
{
  __shared__ int base[E_EXP];
  __shared__ int cnt[E_EXP];
  const int tid = threadIdx.x, blk = blockIdx.x;
  if (tid < E_EXP) { base[tid] = blockBase[blk * E_EXP + tid]; cnt[tid] = 0; }
  __syncthreads();
  const int s0 = blk * (TOT_ROWS / NBLK);
  for (int i = tid; i < TOT_ROWS / NBLK; i += 256) {
    const int s = s0 + i;
    const int e = eids[s];
    const int r = base[e] + atomicAdd(&cnt[e], 1);     // unique row in expert region
    rowmap[r] = s >> 1;                                // token index
    invrow[s] = r;                                     // (token,slot) -> row
  }
}

// ------------- x -> bf16 straight convert (no scatter) ----------------------
__global__ void __launch_bounds__(256) convert_x(
    const float* __restrict__ x, unsigned short* __restrict__ xb)
{
  const size_t i = (size_t)blockIdx.x * 256 + threadIdx.x;   // float4 granularity
  const float4 v = ((const float4*)x)[i];
  ushort4 o;
  o.x = f2bf(v.x); o.y = f2bf(v.y); o.z = f2bf(v.z); o.w = f2bf(v.w);
  ((ushort4*)xb)[i] = o;
}

// --------- weight transpose+convert: src fp32 [E][R][C] -> dst bf16 [E][C][R]
__global__ void __launch_bounds__(256) transpose_conv(
    const float* __restrict__ src, unsigned short* __restrict__ dst, int R, int C)
{
  __shared__ float tile[32][33];
  const int tx = threadIdx.x, ty = threadIdx.y;   // 32 x 8
  const size_t ebase = (size_t)blockIdx.z * R * C;
  const int c0 = blockIdx.x * 32, r0 = blockIdx.y * 32;
  const float* s = src + ebase;
#pragma unroll
  for (int j = 0; j < 4; ++j)
    tile[ty + j * 8][tx] = s[(size_t)(r0 + ty + j * 8) * C + c0 + tx];
  __syncthreads();
  unsigned short* d = dst + ebase;
#pragma unroll
  for (int j = 0; j < 4; ++j)
    d[(size_t)(c0 + ty + j * 8) * R + r0 + tx] = f2bf(tile[tx][ty + j * 8]);
}

__global__ void zero_kernel(float4* __restrict__ p, int n4) {
  const int i = blockIdx.x * blockDim.x + threadIdx.x;
  if (i < n4) p[i] = make_float4(0.f, 0.f, 0.f, 0.f);
}

// ------------------- GEMM1: Hbuf = relu(gather(xb) @ W1t^T + b1) ------------
// m97 structure. 1-D grid with XCD swizzle: the 32 nt-blocks of one m-tile sit
// at blockIdx strides of 8 (same XCD) and adjacent dispatch time -> A-tile
// (256 KB) served from that XCD's 4 MB L2 after first touch.
__global__ void __launch_bounds__(256) gemm1_kernel(
    const unsigned short* __restrict__ xb,    // [T][1024] bf16
    const unsigned short* __restrict__ W1t,   // [E][4096][1024] (n-major, k-contig)
    const float* __restrict__ b1,             // [E][4096]
    unsigned short* __restrict__ Hbuf,        // [TOT][4096]
    const int* __restrict__ offs, const int* __restrict__ rowmap)
{
  __shared__ unsigned short As[128 * 32];
  __shared__ unsigned short Bs[128 * 32];
  // swizzle decode: group of 256 blocks = 8 m-tiles x 32 nt
  const int linear = blockIdx.x;
  const int idx = linear & 255;
  const int mtg = (linear >> 8) * 8 + (idx & 7);   // global m-tile 0..1023
  const int nt  = idx >> 3;                        // 0..31
  const int e  = mtg >> 7;
  const int mt = mtg & 127;
  const int row0 = offs[e];
  const int rows = offs[e + 1] - row0;
  if (mt * 128 >= rows) return;               // early exit on oversized grid

  const int tid = threadIdx.x, wave = tid >> 6, lane = tid & 63;
  const int wm = wave & 1, wn = wave >> 1;
  floatx4 acc[4][4];
  const floatx4 zf = {0.f, 0.f, 0.f, 0.f};
#pragma unroll
  for (int mi = 0; mi < 4; ++mi)
#pragma unroll
    for (int ni = 0; ni < 4; ++ni) acc[mi][ni] = zf;

  const unsigned short* Wb = W1t + ((size_t)e * H_DIM + nt * 128) * D_DIM;
  const int arow = wave * 32 + (lane >> 2);   // row within 128-tile (16 rows/instr)
  const int kcol = (lane & 3) * 8;            // k element offset within BK

  // hoist gathered A-row pointers out of the K-loop
  const unsigned short* aptr[2];
  const unsigned short* bptr[2];
#pragma unroll
  for (int i = 0; i < 2; ++i) {
    const int r = mt * 128 + arow + i * 16;
    const int tok = rowmap[row0 + (r < rows ? r : 0)];   // clamp: valid token
    aptr[i] = xb + (size_t)tok * D_DIM + kcol;
    bptr[i] = Wb + (size_t)(arow + i * 16) * D_DIM + kcol;
  }

  for (int k0 = 0; k0 < D_DIM; k0 += 32) {
    __syncthreads();
#pragma unroll
    for (int i = 0; i < 2; ++i) {
      gload_lds16(aptr[i] + k0, &As[(wave * 32 + i * 16) * 32]);
      gload_lds16(bptr[i] + k0, &Bs[(wave * 32 + i * 16) * 32]);
    }
    __syncthreads();
    bf16x8 af[4], bb[4];
#pragma unroll
    for (int mi = 0; mi < 4; ++mi)
      af[mi] = *(const bf16x8*)&As[(wm * 64 + mi * 16 + (lane & 15)) * 32 + (lane >> 4) * 8];
#pragma unroll
    for (int ni = 0; ni < 4; ++ni)
      bb[ni] = *(const bf16x8*)&Bs[(wn * 64 + ni * 16 + (lane & 15)) * 32 + (lane >> 4) * 8];
#pragma unroll
    for (int mi = 0; mi < 4; ++mi)
#pragma unroll
      for (int ni = 0; ni < 4; ++ni)
        acc[mi][ni] = __builtin_amdgcn_mfma_f32_16x16x32_bf16(af[mi], bb[ni], acc[mi][ni], 0, 0, 0);
  }

  const float* bias = b1 + e * H_DIM;
#pragma unroll
  for (int mi = 0; mi < 4; ++mi) {
    const int rbase = mt * 128 + wm * 64 + mi * 16 + (lane >> 4) * 4;
#pragma unroll
    for (int ni = 0; ni < 4; ++ni) {
      const int n = nt * 128 + wn * 64 + ni * 16 + (lane & 15);
      const floatx4 c = acc[mi][ni];
#pragma unroll
      for (int i = 0; i < 4; ++i) {
        const int r = rbase + i;
        if (r < rows) {
          float v = c[i] + bias[n];
          v = v > 0.f ? v : 0.f;                      // relu
          Hbuf[(size_t)(row0 + r) * H_DIM + n] = f2bf(v);
        }
      }
    }
  }
}

// --------- GEMM2: Ybuf[row] = Hbuf[row] @ W2t^T  (plain bf16 stores) --------
__global__ void __launch_bounds__(256) gemm2_kernel(
    const unsigned short* __restrict__ Hbuf,  // [TOT][4096]
    const unsigned short* __restrict__ W2t,   // [E][1024][4096]
    const int* __restrict__ offs,
    unsigned short* __restrict__ Ybuf)        // [TOT][1024]
{
  __shared__ unsigned short As[128 * 32];
  __shared__ unsigned short Bs[128 * 32];
  // swizzle decode: group of 64 blocks = 8 m-tiles x 8 nt
  const int linear = blockIdx.x;
  const int idx = linear & 63;
  const int mtg = (linear >> 6) * 8 + (idx & 7);   // global m-tile 0..1023
  const int nt  = idx >> 3;                        // 0..7
  const int e  = mtg >> 7;
  const int mt = mtg & 127;
  const int row0 = offs[e];
  const int rows = offs[e + 1] - row0;
  if (mt * 128 >= rows) return;

  const int tid = threadIdx.x, wave = tid >> 6, lane = tid & 63;
  const int wm = wave & 1, wn = wave >> 1;
  floatx4 acc[4][4];
  const floatx4 zf = {0.f, 0.f, 0.f, 0.f};
#pragma unroll
  for (int mi = 0; mi < 4; ++mi)
#pragma unroll
    for (int ni = 0; ni < 4; ++ni) acc[mi][ni] = zf;

  const unsigned short* Wb = W2t + ((size_t)e * D_DIM + nt * 128) * H_DIM;
  const int arow = wave * 32 + (lane >> 2);
  const int kcol = (lane & 3) * 8;

  const unsigned short* aptr[2];
  const unsigned short* bptr[2];
#pragma unroll
  for (int i = 0; i < 2; ++i) {
    int gr = row0 + mt * 128 + arow + i * 16;
    gr = gr < TOT_ROWS - 1 ? gr : TOT_ROWS - 1;        // clamp: never read past Hbuf
    aptr[i] = Hbuf + (size_t)gr * H_DIM + kcol;
    bptr[i] = Wb + (size_t)(arow + i * 16) * H_DIM + kcol;
  }

  for (int k0 = 0; k0 < H_DIM; k0 += 32) {
    __syncthreads();
#pragma unroll
    for (int i = 0; i < 2; ++i) {
      gload_lds16(aptr[i] + k0, &As[(wave * 32 + i * 16) * 32]);
      gload_lds16(bptr[i] + k0, &Bs[(wave * 32 + i * 16) * 32]);
    }
    __syncthreads();
    bf16x8 af[4], bb[4];
#pragma unroll
    for (int mi = 0; mi < 4; ++mi)
      af[mi] = *(const bf16x8*)&As[(wm * 64 + mi * 16 + (lane & 15)) * 32 + (lane >> 4) * 8];
#pragma unroll
    for (int ni = 0; ni < 4; ++ni)
      bb[ni] = *(const bf16x8*)&Bs[(wn * 64 + ni * 16 + (lane & 15)) * 32 + (lane >> 4) * 8];
#pragma unroll
    for (int mi = 0; mi < 4; ++mi)
#pragma unroll
      for (int ni = 0; ni < 4; ++ni)
        acc[mi][ni] = __builtin_amdgcn_mfma_f32_16x16x32_bf16(af[mi], bb[ni], acc[mi][ni], 0, 0, 0);
  }

#pragma unroll
  for (int mi = 0; mi < 4; ++mi) {
    const int rbase = mt * 128 + wm * 64 + mi * 16 + (lane >> 4) * 4;
#pragma unroll
    for (int i = 0; i < 4; ++i) {
      const int r = rbase + i;
      if (r < rows) {
        unsigned short* yrow = Ybuf + (size_t)(row0 + r) * D_DIM;
#pragma unroll
        for (int ni = 0; ni < 4; ++ni) {
          const int n = nt * 128 + wn * 64 + ni * 16 + (lane & 15);
          yrow[n] = f2bf(acc[mi][ni][i]);
        }
      }
    }
  }
}

// --------- combine: out[t] = w0*(y0+b2[e0]) + w1*(y1+b2[e1]) ----------------
__global__ void __launch_bounds__(256) combine_kernel(
    const unsigned short* __restrict__ Ybuf, const int* __restrict__ invrow,
    const int* __restrict__ eids, const float* __restrict__ wgt,
    const float* __restrict__ b2, float* __restrict__ out)
{
  const int t = blockIdx.x, tid = threadIdx.x;
  const int r0 = invrow[t * 2], r1 = invrow[t * 2 + 1];
  const int e0 = eids[t * 2], e1 = eids[t * 2 + 1];
  const float w0 = wgt[t * 2], w1 = wgt[t * 2 + 1];
  const ushort4 y0 = ((const ushort4*)(Ybuf + (size_t)r0 * D_DIM))[tid];
  const ushort4 y1 = ((const ushort4*)(Ybuf + (size_t)r1 * D_DIM))[tid];
  const float4 c0 = ((const float4*)(b2 + e0 * D_DIM))[tid];
  const float4 c1 = ((const float4*)(b2 + e1 * D_DIM))[tid];
  float4 o;
  o.x = w0 * (bf2f(y0.x) + c0.x) + w1 * (bf2f(y1.x) + c1.x);
  o.y = w0 * (bf2f(y0.y) + c0.y) + w1 * (bf2f(y1.y) + c1.y);
  o.z = w0 * (bf2f(y0.z) + c0.z) + w1 * (bf2f(y1.z) + c1.z);
  o.w = w0 * (bf2f(y0.w) + c0.w) + w1 * (bf2f(y1.w) + c1.w);
  ((float4*)(out + (size_t)t * D_DIM))[tid] = o;
}

extern "C" void kernel_launch(void* const* d_in, const int* in_sizes, int n_in,
                              void* d_out, int out_size, void* d_ws, size_t ws_size,
                              hipStream_t stream) {
  const float* x      = (const float*)d_in[0];
  const float* gate_w = (const float*)d_in[1];
  const float* gate_b = (const float*)d_in[2];
  const float* W1     = (const float*)d_in[3];
  const float* b1     = (const float*)d_in[4];
  const float* W2     = (const float*)d_in[5];
  const float* b2     = (const float*)d_in[6];
  float* out = (float*)d_out;

  char* ws = (char*)d_ws;
  const size_t MB = 1024 * 1024;
  int*   offs      = (int*)(ws + 0);                    // [9]
  int*   blockHist = (int*)(ws + 4096);                 // [64*8]
  int*   blockBase = (int*)(ws + 8192);                 // [64*8]
  int*   eids      = (int*)(ws + 16384);                // [T*2] = 128 KB
  float* wgt       = (float*)(ws + 16384 + 131072);     // [T*2]
  int*   rowmap    = (int*)(ws + 16384 + 262144);       // [TOT]
  int*   invrow    = (int*)(ws + 16384 + 393216);       // [TOT]
  unsigned short* xb   = (unsigned short*)(ws + MB);                    // 32 MB
  unsigned short* Hbuf = (unsigned short*)(ws + MB + 32 * MB);          // 256 MB
  unsigned short* W1t  = (unsigned short*)(ws + MB + (32 + 256) * MB);  // 64 MB
  unsigned short* W2t  = (unsigned short*)(ws + MB + (32 + 256 + 64) * MB); // 64 MB
  unsigned short* Ybuf = W1t;   // W1t is dead after gemm1; Ybuf overlays it (64 MB)
  const size_t need = MB + (32 + 256 + 64 + 64) * MB;

  if (ws_size < need) {  // signals ws shortage (out zeroed) without OOB writes
    zero_kernel<<<(out_size / 4 + 255) / 256, 256, 0, stream>>>((float4*)out, out_size / 4);
    return;
  }

  gate_kernel<<<T_TOK / 4, 256, 0, stream>>>(x, gate_w, gate_b, eids, wgt);
  hist_kernel<<<NBLK, 256, 0, stream>>>(eids, blockHist);
  prefix_kernel<<<1, 64, 0, stream>>>(blockHist, blockBase, offs);
  assign_kernel<<<NBLK, 256, 0, stream>>>(eids, wgt, blockBase, rowmap, invrow);
  convert_x<<<(T_TOK * D_DIM / 4) / 256, 256, 0, stream>>>(x, xb);
  transpose_conv<<<dim3(H_DIM / 32, D_DIM / 32, E_EXP), dim3(32, 8), 0, stream>>>(W1, W1t, D_DIM, H_DIM);
  transpose_conv<<<dim3(D_DIM / 32, H_DIM / 32, E_EXP), dim3(32, 8), 0, stream>>>(W2, W2t, H_DIM, D_DIM);
  gemm1_kernel<<<E_EXP * 128 * 32, 256, 0, stream>>>(xb, W1t, b1, Hbuf, offs, rowmap);
  gemm2_kernel<<<E_EXP * 128 * 8, 256, 0, stream>>>(Hbuf, W2t, offs, Ybuf);
  combine_kernel<<<T_TOK, 256, 0, stream>>>(Ybuf, invrow, eids, wgt, b2, out);
}